// Round 10
// baseline (956.000 us; speedup 1.0000x reference)
//
#include <hip/hip_runtime.h>

typedef float f32x4 __attribute__((ext_vector_type(4)));
typedef short bf16x8 __attribute__((ext_vector_type(8)));

#define INV_TEMP 14.285714285714286f
#define M_REF    14.285714285714286f

static constexpr size_t OUT_PRED   = 0;
static constexpr size_t OUT_LOSS   = 409600;
static constexpr size_t OUT_LOGITS = 409601;
static constexpr size_t OUT_LPROTO = 268849153;
static constexpr size_t OUT_NEWQ   = 269258753;
static constexpr size_t OUT_NPROTO = 277647361;

__device__ __forceinline__ unsigned f2bf(float x){
  unsigned u = __float_as_uint(x);
  return (u + 0x7fffu + ((u >> 16) & 1u)) >> 16;   // RTNE
}

// ---------- prep: conv_qT (bid<1024) | conv_q (bid<1280) | lpos (else) ----------
__global__ __launch_bounds__(256) void prep_k(const float* __restrict__ q, const float* __restrict__ kk,
                                              const float* __restrict__ queue,
                                              unsigned short* __restrict__ qbf,
                                              unsigned short* __restrict__ qTbf,
                                              float* __restrict__ out, float* __restrict__ lposw){
  __shared__ float tile[128][65];
  const int bid = blockIdx.x, t = threadIdx.x;
  if (bid < 1024){                                  // queue [128][65536] -> qTbf [65536][128] bf16
    const int j0 = bid*64;
    #pragma unroll
    for (int it=0; it<8; ++it){                     // float4 reads: 128 rows x 16 f4
      int idx = it*256 + t;
      int d = idx >> 4, jj = (idx & 15)*4;
      float4 v = *(const float4*)(queue + (size_t)d*65536 + j0 + jj);
      tile[d][jj] = v.x; tile[d][jj+1] = v.y; tile[d][jj+2] = v.z; tile[d][jj+3] = v.w;
    }
    __syncthreads();
    #pragma unroll
    for (int it=0; it<8; ++it){                     // uint2 writes: 64 j x 32 d-quads
      int pidx = it*256 + t;
      int j = pidx >> 5, dq = (pidx & 31)*4;
      uint2 pk;
      pk.x = f2bf(tile[dq][j])   | (f2bf(tile[dq+1][j]) << 16);
      pk.y = f2bf(tile[dq+2][j]) | (f2bf(tile[dq+3][j]) << 16);
      *(uint2*)(qTbf + (size_t)(j0+j)*128 + dq) = pk;
    }
  } else if (bid < 1280){                           // q -> bf16
    int i = (bid-1024)*256 + t;
    const float4* q4 = (const float4*)q;
    float4 a = q4[2*i], b = q4[2*i+1];
    int4 st;
    st.x = (int)(f2bf(a.x) | (f2bf(a.y) << 16));
    st.y = (int)(f2bf(a.z) | (f2bf(a.w) << 16));
    st.z = (int)(f2bf(b.x) | (f2bf(b.y) << 16));
    st.w = (int)(f2bf(b.z) | (f2bf(b.w) << 16));
    ((int4*)qbf)[i] = st;
  } else {                                          // l_pos: 4 rows per block, 1 wave per row
    const int r = (bid-1280)*4 + (t>>6), l = t & 63;
    const float2* q2 = (const float2*)(q + (size_t)r*128);
    const float2* k2 = (const float2*)(kk + (size_t)r*128);
    float2 a = q2[l], b = k2[l];
    float s = a.x*b.x + a.y*b.y;
    #pragma unroll
    for (int o=1;o<64;o<<=1) s += __shfl_xor(s, o, 64);
    if (l == 0){
      float v = s * INV_TEMP;
      out[OUT_LOGITS + (size_t)r*65537] = v;
      lposw[r] = v;
    }
  }
}

// ---------- big GEMM: logits[:,1:] = (q @ queue)/TEMP, fused row sum-exp partials ----------
// R10: IDENTICAL to R9's gemm (best: ~338us implied). gridDim.z=3 PROBE to surface
// counters above the harness fills (z>0 duplicates store identical values; benign,
// deterministic; validated in R2/R7). Decomposition: (dur - rest)/3... resolves the
// misaligned-store vs RMW vs VALU question before the next structural edit.
__global__ __launch_bounds__(512, 4) void gemm_k(const unsigned short* __restrict__ qbf,
                                                 const unsigned short* __restrict__ qTbf,
                                                 float* __restrict__ out,
                                                 float* __restrict__ partials){
  __shared__ unsigned char smem[65536];            // A 32KB | B 32KB, XOR-swizzled
  const int cbr = blockIdx.x;
  const int cb  = ((cbr & 7) << 6) | (cbr >> 3);   // XCD-chunked
  const int rb  = blockIdx.y;
  const int t   = threadIdx.x;
  const unsigned char* asrc = (const unsigned char*)qbf  + (size_t)rb*32768;
  const unsigned char* bsrc = (const unsigned char*)qTbf + (size_t)cb*32768;
  #pragma unroll
  for (int i=0;i<4;++i){
    int X = i*8192 + t*16;
    int row = X >> 8, off = X & 255;
    int sw = (row << 8) | (off ^ ((row & 7) << 4));
    *(bf16x8*)(smem + sw)         = *(const bf16x8*)(asrc + X);
    *(bf16x8*)(smem + 32768 + sw) = *(const bf16x8*)(bsrc + X);
  }
  __syncthreads();                                  // the only barrier
  const int l = t & 63, wid = t >> 6;               // 8 waves, wave owns 16 rows
  const int lrow = l & 15, lk = l >> 4;

  f32x4 acc[8];
  #pragma unroll
  for (int n=0;n<8;++n) acc[n] = (f32x4){0.f,0.f,0.f,0.f};
  #pragma unroll
  for (int kk2=0; kk2<4; ++kk2){
    const int koff = kk2*64 + lk*16;
    const int arow = wid*16 + lrow;
    bf16x8 af = *(const bf16x8*)(smem + ((arow << 8) | (koff ^ ((arow & 7) << 4))));
    bf16x8 bfr[8];
    #pragma unroll
    for (int n=0;n<8;++n){
      int col = n*16 + lrow;
      bfr[n] = *(const bf16x8*)(smem + 32768 + ((col << 8) | (koff ^ ((col & 7) << 4))));
    }
    #pragma unroll
    for (int n=0;n<8;++n)
      acc[n] = __builtin_amdgcn_mfma_f32_16x16x32_bf16(af, bfr[n], acc[n], 0, 0, 0);
  }
  // epilogue — no barriers, plain scalar stores (R2 microshape, measured amp 1.00x)
  #pragma unroll
  for (int r=0;r<4;++r){
    const size_t R = (size_t)rb*128 + wid*16 + lk*4 + r;         // global row
    float* p = out + OUT_LOGITS + R*65537 + 1 + (size_t)cb*128;
    float s = 0.f;
    #pragma unroll
    for (int n=0;n<8;++n){
      float v = acc[n][r] * INV_TEMP;
      p[n*16 + lrow] = v;
      s += __expf(v - M_REF);
    }
    #pragma unroll
    for (int o=1;o<16;o<<=1) s += __shfl_xor(s, o, 64);          // 16-lane row sum
    if (lrow == 0) partials[(size_t)cb*4096 + R] = s;
  }
}

// ---------- post: protos EMA (bid<100) | k6 (bid<4196) | rowsum (else) ----------
__global__ __launch_bounds__(128) void post_k(const float* __restrict__ q, const float* __restrict__ outp_in,
                                              const float* __restrict__ protos, const float* __restrict__ labels,
                                              const int* __restrict__ targets,
                                              const float* __restrict__ partials, const float* __restrict__ lposw,
                                              float* __restrict__ out, float* __restrict__ lcw,
                                              float* __restrict__ lpw, float* __restrict__ instw){
  __shared__ int   tg[4096];
  __shared__ int   mlist[4096];
  __shared__ int   cnt[128];
  __shared__ float red[128];
  __shared__ float qs[128];
  __shared__ float w2[2];
  const int bid = blockIdx.x, t = threadIdx.x;
  if (bid < 100){                                   // per-class prototype EMA via stable match list
    const int c = bid;
    for (int i=t;i<4096;i+=128) tg[i] = targets[i];
    __syncthreads();
    int myc = 0;
    #pragma unroll 4
    for (int i=0;i<32;++i) if (tg[t*32+i] == c) myc++;
    cnt[t] = myc; __syncthreads();
    // inclusive scan over 128 threads
    for (int s=1; s<128; s<<=1){
      int v = (t >= s) ? cnt[t-s] : 0;
      __syncthreads();
      cnt[t] += v;
      __syncthreads();
    }
    const int base = cnt[t] - myc;
    const int total = cnt[127];
    int k2 = base;
    for (int i=0;i<32;++i){
      int n = t*32 + i;
      if (tg[n] == c) mlist[k2++] = n;              // stable order: n ascending
    }
    __syncthreads();
    float val = protos[(size_t)c*128 + t];
    if (c != 0){
      for (int i=0;i<total;++i){
        int n = mlist[i];
        val = val*0.999f + 0.001f*q[(size_t)n*128 + t];
      }
    }
    red[t] = val*val; __syncthreads();
    #pragma unroll
    for (int s=64;s>0;s>>=1){ if (t < s) red[t] += red[t+s]; __syncthreads(); }
    float nrm = fmaxf(sqrtf(red[0]), 1e-12f);
    out[OUT_NPROTO + (size_t)c*128 + t] = val / nrm;
  } else if (bid < 4196){                           // logits_proto + both soft-CE rows + pred
    const int r = bid - 100;
    const int lane = t & 63, wid = t >> 6;
    qs[t] = q[(size_t)r*128 + t];
    __syncthreads();
    const bool act = t < 100;
    auto wmax = [&](float v)->float{
      #pragma unroll
      for (int o=1;o<64;o<<=1) v = fmaxf(v, __shfl_xor(v, o, 64));
      if (lane == 0) w2[wid] = v;
      __syncthreads();
      float rr = fmaxf(w2[0], w2[1]);
      __syncthreads();
      return rr;
    };
    auto wsum = [&](float v)->float{
      #pragma unroll
      for (int o=1;o<64;o<<=1) v += __shfl_xor(v, o, 64);
      if (lane == 0) w2[wid] = v;
      __syncthreads();
      float rr = w2[0] + w2[1];
      __syncthreads();
      return rr;
    };
    float p = 0.f;
    if (act){
      const float4* pr = (const float4*)(protos + (size_t)t*128);
      const float4* qv = (const float4*)qs;
      float s = 0.f;
      #pragma unroll 8
      for (int i=0;i<32;++i){ float4 a=qv[i], b=pr[i]; s += a.x*b.x + a.y*b.y + a.z*b.z + a.w*b.w; }
      p = s * INV_TEMP;
      out[OUT_LPROTO + (size_t)r*100 + t] = p;
    }
    const float lab = act ? labels[(size_t)r*100 + t] : 0.f;
    const float o   = act ? outp_in[(size_t)r*100 + t] : 0.f;
    float mx  = wmax(act ? p : -3.0e38f);
    float se  = wsum(act ? __expf(p - mx) : 0.f);
    float lse = mx + logf(se);
    float lpv = wsum(act ? lab * (p - lse) : 0.f);
    float mo   = wmax(act ? o : -3.0e38f);
    float seo  = wsum(act ? __expf(o - mo) : 0.f);
    float lseo = mo + logf(seo);
    float lcv  = wsum(act ? lab * (o - lseo) : 0.f);
    if (act) out[OUT_PRED + (size_t)r*100 + t] = (t > 0 && o >= mo) ? 1.f : 0.f;
    if (t == 0){ lpw[r] = lpv; lcw[r] = lcv; }
  } else {                                          // rowsum: inst log-softmax term
    const int r = (bid - 4196)*128 + t;
    float s = 0.f;
    for (int cbq=0; cbq<512; ++cbq) s += partials[(size_t)cbq*4096 + r];
    s += __expf(lposw[r] - M_REF);
    instw[r] = lposw[r] - M_REF - logf(s);
  }
}

// ---------- final scalar loss ----------
__global__ __launch_bounds__(256) void loss_k(const float* __restrict__ lcw, const float* __restrict__ lpw,
                                              const float* __restrict__ instw, float* __restrict__ out){
  __shared__ float red[256];
  const int t = threadIdx.x;
  float s = 0.f;
  for (int r=t;r<4096;r+=256) s += lcw[r] + lpw[r] + instw[r];
  red[t] = s; __syncthreads();
  for (int k2=128;k2>0;k2>>=1){ if (t<k2) red[t] += red[t+k2]; __syncthreads(); }
  if (t==0) out[OUT_LOSS] = -red[0] * (1.0f/4096.0f);
}

// ---------- new_queue: kt splice (bid<64) | copy (else, float4) ----------
__global__ __launch_bounds__(256) void newq_k(const float* __restrict__ queue, const float* __restrict__ kk,
                                              const int* __restrict__ ptrp, float* __restrict__ out){
  __shared__ float tile[64][129];
  const int bid = blockIdx.x, t = threadIdx.x;
  const int ptr = *ptrp;
  if (bid < 64){                                    // k.T into columns [ptr, ptr+4096)
    const int jb = bid;
    for (int it=0; it<32; ++it){
      int idx = it*256 + t;
      int j = idx >> 7, d = idx & 127;
      tile[j][d] = kk[(size_t)(jb*64 + j)*128 + d];
    }
    __syncthreads();
    for (int it=0; it<32; ++it){
      int idx = it*256 + t;
      int d = idx >> 6, j = idx & 63;
      out[OUT_NEWQ + (size_t)d*65536 + (size_t)(ptr + jb*64 + j)] = tile[j][d];
    }
  } else {                                          // copy outside splice, float4
    size_t tid4 = (size_t)(bid-64)*256 + t;
    for (size_t i4=tid4; i4<(size_t)2097152; i4 += (size_t)4096*256){
      size_t i = i4*4;
      int c = (int)(i & 65535);
      int lo = c - ptr;                              // elems lo..lo+3 vs [0,4096)
      if (lo + 3 < 0 || lo >= 4096){
        *(float4*)(out + OUT_NEWQ + i) = *(const float4*)(queue + i);
      } else {
        #pragma unroll
        for (int e=0;e<4;++e){
          int x = lo + e;
          if (x < 0 || x >= 4096) out[OUT_NEWQ + i + e] = queue[i + e];
        }
      }
    }
  }
}

extern "C" void kernel_launch(void* const* d_in, const int* in_sizes, int n_in,
                              void* d_out, int out_size, void* d_ws, size_t ws_size,
                              hipStream_t stream){
  const float* q      = (const float*)d_in[0];
  const float* k      = (const float*)d_in[1];
  const float* outp   = (const float*)d_in[2];
  const float* queue  = (const float*)d_in[3];
  const float* protos = (const float*)d_in[4];
  const float* labels = (const float*)d_in[5];
  const int*   targets= (const int*)d_in[6];
  const int*   ptrp   = (const int*)d_in[7];
  float* out = (float*)d_out;

  // Scratch lives inside the new_queue OUTPUT region (32 MiB; we use ~25.1 MiB).
  // new_queue is written LAST, after every scratch consumer has finished.
  uintptr_t scr = (uintptr_t)(out + OUT_NEWQ);
  scr = (scr + 255) & ~(uintptr_t)255;
  unsigned short* qbf  = (unsigned short*)scr;                          // 1 MB
  unsigned short* qTbf = (unsigned short*)(scr + (1u<<20));             // 16 MB
  float* partials      = (float*)(scr + (1u<<20) + (16u<<20));          // 8 MB
  float* lposw         = (float*)(scr + 26214400u);                     // 16 KB
  float* lcw           = (float*)(scr + 26230784u);                     // 16 KB
  float* lpw           = (float*)(scr + 26247168u);                     // 16 KB
  float* instw         = (float*)(scr + 26263552u);                     // 16 KB

  prep_k <<<2304, 256, 0, stream>>>(q, k, queue, qbf, qTbf, out, lposw);
  gemm_k <<<dim3(512,32,3), 512, 0, stream>>>(qbf, qTbf, out, partials);  // z=3: probe
  post_k <<<4228, 128, 0, stream>>>(q, outp, protos, labels, targets, partials, lposw,
                                    out, lcw, lpw, instw);
  loss_k <<<1, 256, 0, stream>>>(lcw, lpw, instw, out);
  newq_k <<<4160, 256, 0, stream>>>(queue, k, ptrp, out);

  (void)in_sizes; (void)n_in; (void)d_ws; (void)ws_size; (void)out_size;
}

// Round 11
// 418.664 us; speedup vs baseline: 2.2835x; 2.2835x over previous
//
#include <hip/hip_runtime.h>

typedef float f32x4 __attribute__((ext_vector_type(4)));
typedef short bf16x8 __attribute__((ext_vector_type(8)));

#define INV_TEMP 14.285714285714286f
#define M_REF    14.285714285714286f

static constexpr size_t OUT_PRED   = 0;
static constexpr size_t OUT_LOSS   = 409600;
static constexpr size_t OUT_LOGITS = 409601;
static constexpr size_t OUT_LPROTO = 268849153;
static constexpr size_t OUT_NEWQ   = 269258753;
static constexpr size_t OUT_NPROTO = 277647361;

__device__ __forceinline__ unsigned f2bf(float x){
  unsigned u = __float_as_uint(x);
  return (u + 0x7fffu + ((u >> 16) & 1u)) >> 16;   // RTNE
}

// ---------- prep: conv_qT (bid<1024) | conv_q (bid<1280) | lpos (else) ----------
__global__ __launch_bounds__(256) void prep_k(const float* __restrict__ q, const float* __restrict__ kk,
                                              const float* __restrict__ queue,
                                              unsigned short* __restrict__ qbf,
                                              unsigned short* __restrict__ qTbf,
                                              float* __restrict__ out, float* __restrict__ lposw){
  __shared__ float tile[128][65];
  const int bid = blockIdx.x, t = threadIdx.x;
  if (bid < 1024){                                  // queue [128][65536] -> qTbf [65536][128] bf16
    const int j0 = bid*64;
    #pragma unroll
    for (int it=0; it<8; ++it){                     // float4 reads: 128 rows x 16 f4
      int idx = it*256 + t;
      int d = idx >> 4, jj = (idx & 15)*4;
      float4 v = *(const float4*)(queue + (size_t)d*65536 + j0 + jj);
      tile[d][jj] = v.x; tile[d][jj+1] = v.y; tile[d][jj+2] = v.z; tile[d][jj+3] = v.w;
    }
    __syncthreads();
    #pragma unroll
    for (int it=0; it<8; ++it){                     // uint2 writes: 64 j x 32 d-quads
      int pidx = it*256 + t;
      int j = pidx >> 5, dq = (pidx & 31)*4;
      uint2 pk;
      pk.x = f2bf(tile[dq][j])   | (f2bf(tile[dq+1][j]) << 16);
      pk.y = f2bf(tile[dq+2][j]) | (f2bf(tile[dq+3][j]) << 16);
      *(uint2*)(qTbf + (size_t)(j0+j)*128 + dq) = pk;
    }
  } else if (bid < 1280){                           // q -> bf16
    int i = (bid-1024)*256 + t;
    const float4* q4 = (const float4*)q;
    float4 a = q4[2*i], b = q4[2*i+1];
    int4 st;
    st.x = (int)(f2bf(a.x) | (f2bf(a.y) << 16));
    st.y = (int)(f2bf(a.z) | (f2bf(a.w) << 16));
    st.z = (int)(f2bf(b.x) | (f2bf(b.y) << 16));
    st.w = (int)(f2bf(b.z) | (f2bf(b.w) << 16));
    ((int4*)qbf)[i] = st;
  } else {                                          // l_pos: 4 rows per block, 1 wave per row
    const int r = (bid-1280)*4 + (t>>6), l = t & 63;
    const float2* q2 = (const float2*)(q + (size_t)r*128);
    const float2* k2 = (const float2*)(kk + (size_t)r*128);
    float2 a = q2[l], b = k2[l];
    float s = a.x*b.x + a.y*b.y;
    #pragma unroll
    for (int o=1;o<64;o<<=1) s += __shfl_xor(s, o, 64);
    if (l == 0){
      float v = s * INV_TEMP;
      out[OUT_LOGITS + (size_t)r*65537] = v;
      lposw[r] = v;
    }
  }
}

// ---------- big GEMM: logits[:,1:] = (q @ queue)/TEMP, fused row sum-exp partials ----------
// R11 (from R10 probe: WRITE amp 1.00x clean; FETCH 264MB/unit = B re-fetched ~16x,
// interleaved with the 1.07GB write stream -> HBM at 58% mixed-traffic): cb-PERSISTENT
// blocks. 512 blocks (2/CU), each stages its 32KB B tile ONCE (one barrier total) and
// loops all 32 rb. A read to REGISTERS per rb (L2-hot 1MB; 64B-aligned dwordx4), with
// 2-deep ping-pong prefetch so the vmcnt wait for A does NOT drain the epilogue stores
// (the R4/R7 serialization). Scalar stores (proven amp 1.00x). FETCH -> ~16MB B + A.
__global__ __launch_bounds__(512) void gemm_k(const unsigned short* __restrict__ qbf,
                                              const unsigned short* __restrict__ qTbf,
                                              float* __restrict__ out,
                                              float* __restrict__ partials){
  __shared__ unsigned char smem[32768];            // B tile only, XOR-swizzled
  const int cbr = blockIdx.x;
  const int cb  = ((cbr & 7) << 6) | (cbr >> 3);   // XCD-chunked
  const int t   = threadIdx.x;
  const unsigned char* bsrc = (const unsigned char*)qTbf + (size_t)cb*32768;
  #pragma unroll
  for (int i=0;i<4;++i){
    int X = i*8192 + t*16;
    int row = X >> 8, off = X & 255;
    int sw = (row << 8) | (off ^ ((row & 7) << 4));
    *(bf16x8*)(smem + sw) = *(const bf16x8*)(bsrc + X);
  }
  __syncthreads();                                  // the only barrier
  const int l = t & 63, wid = t >> 6;               // 8 waves, wave owns 16 rows of each rb-tile
  const int lrow = l & 15, lk = l >> 4;
  const unsigned char* aBase = (const unsigned char*)qbf + ((wid*16 + lrow) << 8) + lk*16;

#define LOADA(dst, rbv)                                                          \
  {                                                                              \
    const unsigned char* aP = aBase + (size_t)(rbv)*32768;                       \
    dst##0 = *(const bf16x8*)(aP);                                               \
    dst##1 = *(const bf16x8*)(aP + 64);                                          \
    dst##2 = *(const bf16x8*)(aP + 128);                                         \
    dst##3 = *(const bf16x8*)(aP + 192);                                         \
  }

#define COMPUTE(src, rbv)                                                        \
  {                                                                              \
    f32x4 acc[8];                                                                \
    _Pragma("unroll")                                                            \
    for (int n=0;n<8;++n) acc[n] = (f32x4){0.f,0.f,0.f,0.f};                     \
    _Pragma("unroll")                                                            \
    for (int kk2=0; kk2<4; ++kk2){                                               \
      const int koff = kk2*64 + lk*16;                                           \
      bf16x8 af = (kk2==0)?src##0:(kk2==1)?src##1:(kk2==2)?src##2:src##3;        \
      _Pragma("unroll")                                                          \
      for (int n=0;n<8;++n){                                                     \
        int col = n*16 + lrow;                                                   \
        bf16x8 bfr = *(const bf16x8*)(smem + ((col << 8) | (koff ^ ((col & 7) << 4)))); \
        acc[n] = __builtin_amdgcn_mfma_f32_16x16x32_bf16(af, bfr, acc[n], 0, 0, 0); \
      }                                                                          \
    }                                                                            \
    _Pragma("unroll")                                                            \
    for (int r=0;r<4;++r){                                                       \
      const size_t R = (size_t)(rbv)*128 + wid*16 + lk*4 + r;                    \
      float* p = out + OUT_LOGITS + R*65537 + 1 + (size_t)cb*128;                \
      float s = 0.f;                                                             \
      _Pragma("unroll")                                                          \
      for (int n=0;n<8;++n){                                                     \
        float v = acc[n][r] * INV_TEMP;                                          \
        p[n*16 + lrow] = v;                                                      \
        s += __expf(v - M_REF);                                                  \
      }                                                                          \
      _Pragma("unroll")                                                          \
      for (int o=1;o<16;o<<=1) s += __shfl_xor(s, o, 64);                        \
      if (lrow == 0) partials[(size_t)cb*4096 + R] = s;                          \
    }                                                                            \
  }

  bf16x8 a0_0, a0_1, a0_2, a0_3;
  bf16x8 a1_0, a1_1, a1_2, a1_3;
  LOADA(a0_, 0)
  for (int rb=0; rb<32; rb+=2){
    LOADA(a1_, rb+1)                  // issued BEFORE rb's stores: vmcnt wait for a1
    COMPUTE(a0_, rb)                  // won't drain them
    if (rb+2 < 32) LOADA(a0_, rb+2)
    COMPUTE(a1_, rb+1)
  }
#undef LOADA
#undef COMPUTE
}

// ---------- post: protos EMA (bid<100) | k6 (bid<4196) | rowsum (else) ----------
__global__ __launch_bounds__(128) void post_k(const float* __restrict__ q, const float* __restrict__ outp_in,
                                              const float* __restrict__ protos, const float* __restrict__ labels,
                                              const int* __restrict__ targets,
                                              const float* __restrict__ partials, const float* __restrict__ lposw,
                                              float* __restrict__ out, float* __restrict__ lcw,
                                              float* __restrict__ lpw, float* __restrict__ instw){
  __shared__ int   tg[4096];
  __shared__ int   mlist[4096];
  __shared__ int   cnt[128];
  __shared__ float red[128];
  __shared__ float qs[128];
  __shared__ float w2[2];
  const int bid = blockIdx.x, t = threadIdx.x;
  if (bid < 100){                                   // per-class prototype EMA via stable match list
    const int c = bid;
    for (int i=t;i<4096;i+=128) tg[i] = targets[i];
    __syncthreads();
    int myc = 0;
    #pragma unroll 4
    for (int i=0;i<32;++i) if (tg[t*32+i] == c) myc++;
    cnt[t] = myc; __syncthreads();
    // inclusive scan over 128 threads
    for (int s=1; s<128; s<<=1){
      int v = (t >= s) ? cnt[t-s] : 0;
      __syncthreads();
      cnt[t] += v;
      __syncthreads();
    }
    const int base = cnt[t] - myc;
    const int total = cnt[127];
    int k2 = base;
    for (int i=0;i<32;++i){
      int n = t*32 + i;
      if (tg[n] == c) mlist[k2++] = n;              // stable order: n ascending
    }
    __syncthreads();
    float val = protos[(size_t)c*128 + t];
    if (c != 0){
      for (int i=0;i<total;++i){
        int n = mlist[i];
        val = val*0.999f + 0.001f*q[(size_t)n*128 + t];
      }
    }
    red[t] = val*val; __syncthreads();
    #pragma unroll
    for (int s=64;s>0;s>>=1){ if (t < s) red[t] += red[t+s]; __syncthreads(); }
    float nrm = fmaxf(sqrtf(red[0]), 1e-12f);
    out[OUT_NPROTO + (size_t)c*128 + t] = val / nrm;
  } else if (bid < 4196){                           // logits_proto + both soft-CE rows + pred
    const int r = bid - 100;
    const int lane = t & 63, wid = t >> 6;
    qs[t] = q[(size_t)r*128 + t];
    __syncthreads();
    const bool act = t < 100;
    auto wmax = [&](float v)->float{
      #pragma unroll
      for (int o=1;o<64;o<<=1) v = fmaxf(v, __shfl_xor(v, o, 64));
      if (lane == 0) w2[wid] = v;
      __syncthreads();
      float rr = fmaxf(w2[0], w2[1]);
      __syncthreads();
      return rr;
    };
    auto wsum = [&](float v)->float{
      #pragma unroll
      for (int o=1;o<64;o<<=1) v += __shfl_xor(v, o, 64);
      if (lane == 0) w2[wid] = v;
      __syncthreads();
      float rr = w2[0] + w2[1];
      __syncthreads();
      return rr;
    };
    float p = 0.f;
    if (act){
      const float4* pr = (const float4*)(protos + (size_t)t*128);
      const float4* qv = (const float4*)qs;
      float s = 0.f;
      #pragma unroll 8
      for (int i=0;i<32;++i){ float4 a=qv[i], b=pr[i]; s += a.x*b.x + a.y*b.y + a.z*b.z + a.w*b.w; }
      p = s * INV_TEMP;
      out[OUT_LPROTO + (size_t)r*100 + t] = p;
    }
    const float lab = act ? labels[(size_t)r*100 + t] : 0.f;
    const float o   = act ? outp_in[(size_t)r*100 + t] : 0.f;
    float mx  = wmax(act ? p : -3.0e38f);
    float se  = wsum(act ? __expf(p - mx) : 0.f);
    float lse = mx + logf(se);
    float lpv = wsum(act ? lab * (p - lse) : 0.f);
    float mo   = wmax(act ? o : -3.0e38f);
    float seo  = wsum(act ? __expf(o - mo) : 0.f);
    float lseo = mo + logf(seo);
    float lcv  = wsum(act ? lab * (o - lseo) : 0.f);
    if (act) out[OUT_PRED + (size_t)r*100 + t] = (t > 0 && o >= mo) ? 1.f : 0.f;
    if (t == 0){ lpw[r] = lpv; lcw[r] = lcv; }
  } else {                                          // rowsum: inst log-softmax term
    const int r = (bid - 4196)*128 + t;
    float s = 0.f;
    for (int cbq=0; cbq<512; ++cbq) s += partials[(size_t)cbq*4096 + r];
    s += __expf(lposw[r] - M_REF);
    instw[r] = lposw[r] - M_REF - logf(s);
  }
}

// ---------- final scalar loss ----------
__global__ __launch_bounds__(256) void loss_k(const float* __restrict__ lcw, const float* __restrict__ lpw,
                                              const float* __restrict__ instw, float* __restrict__ out){
  __shared__ float red[256];
  const int t = threadIdx.x;
  float s = 0.f;
  for (int r=t;r<4096;r+=256) s += lcw[r] + lpw[r] + instw[r];
  red[t] = s; __syncthreads();
  for (int k2=128;k2>0;k2>>=1){ if (t<k2) red[t] += red[t+k2]; __syncthreads(); }
  if (t==0) out[OUT_LOSS] = -red[0] * (1.0f/4096.0f);
}

// ---------- new_queue: kt splice (bid<64) | copy (else, float4) ----------
__global__ __launch_bounds__(256) void newq_k(const float* __restrict__ queue, const float* __restrict__ kk,
                                              const int* __restrict__ ptrp, float* __restrict__ out){
  __shared__ float tile[64][129];
  const int bid = blockIdx.x, t = threadIdx.x;
  const int ptr = *ptrp;
  if (bid < 64){                                    // k.T into columns [ptr, ptr+4096)
    const int jb = bid;
    for (int it=0; it<32; ++it){
      int idx = it*256 + t;
      int j = idx >> 7, d = idx & 127;
      tile[j][d] = kk[(size_t)(jb*64 + j)*128 + d];
    }
    __syncthreads();
    for (int it=0; it<32; ++it){
      int idx = it*256 + t;
      int d = idx >> 6, j = idx & 63;
      out[OUT_NEWQ + (size_t)d*65536 + (size_t)(ptr + jb*64 + j)] = tile[j][d];
    }
  } else {                                          // copy outside splice, float4
    size_t tid4 = (size_t)(bid-64)*256 + t;
    for (size_t i4=tid4; i4<(size_t)2097152; i4 += (size_t)4096*256){
      size_t i = i4*4;
      int c = (int)(i & 65535);
      int lo = c - ptr;                              // elems lo..lo+3 vs [0,4096)
      if (lo + 3 < 0 || lo >= 4096){
        *(float4*)(out + OUT_NEWQ + i) = *(const float4*)(queue + i);
      } else {
        #pragma unroll
        for (int e=0;e<4;++e){
          int x = lo + e;
          if (x < 0 || x >= 4096) out[OUT_NEWQ + i + e] = queue[i + e];
        }
      }
    }
  }
}

extern "C" void kernel_launch(void* const* d_in, const int* in_sizes, int n_in,
                              void* d_out, int out_size, void* d_ws, size_t ws_size,
                              hipStream_t stream){
  const float* q      = (const float*)d_in[0];
  const float* k      = (const float*)d_in[1];
  const float* outp   = (const float*)d_in[2];
  const float* queue  = (const float*)d_in[3];
  const float* protos = (const float*)d_in[4];
  const float* labels = (const float*)d_in[5];
  const int*   targets= (const int*)d_in[6];
  const int*   ptrp   = (const int*)d_in[7];
  float* out = (float*)d_out;

  // Scratch lives inside the new_queue OUTPUT region (32 MiB; we use ~25.1 MiB).
  // new_queue is written LAST, after every scratch consumer has finished.
  uintptr_t scr = (uintptr_t)(out + OUT_NEWQ);
  scr = (scr + 255) & ~(uintptr_t)255;
  unsigned short* qbf  = (unsigned short*)scr;                          // 1 MB
  unsigned short* qTbf = (unsigned short*)(scr + (1u<<20));             // 16 MB
  float* partials      = (float*)(scr + (1u<<20) + (16u<<20));          // 8 MB
  float* lposw         = (float*)(scr + 26214400u);                     // 16 KB
  float* lcw           = (float*)(scr + 26230784u);                     // 16 KB
  float* lpw           = (float*)(scr + 26247168u);                     // 16 KB
  float* instw         = (float*)(scr + 26263552u);                     // 16 KB

  prep_k <<<2304, 256, 0, stream>>>(q, k, queue, qbf, qTbf, out, lposw);
  gemm_k <<<512, 512, 0, stream>>>(qbf, qTbf, out, partials);
  post_k <<<4228, 128, 0, stream>>>(q, outp, protos, labels, targets, partials, lposw,
                                    out, lcw, lpw, instw);
  loss_k <<<1, 256, 0, stream>>>(lcw, lpw, instw, out);
  newq_k <<<4160, 256, 0, stream>>>(queue, k, ptrp, out);

  (void)in_sizes; (void)n_in; (void)d_ws; (void)ws_size; (void)out_size;
}

// Round 12
// 380.628 us; speedup vs baseline: 2.5116x; 1.0999x over previous
//
#include <hip/hip_runtime.h>

typedef float f32x4 __attribute__((ext_vector_type(4)));
typedef short bf16x8 __attribute__((ext_vector_type(8)));

#define INV_TEMP 14.285714285714286f
#define M_REF    14.285714285714286f

static constexpr size_t OUT_PRED   = 0;
static constexpr size_t OUT_LOSS   = 409600;
static constexpr size_t OUT_LOGITS = 409601;
static constexpr size_t OUT_LPROTO = 268849153;
static constexpr size_t OUT_NEWQ   = 269258753;
static constexpr size_t OUT_NPROTO = 277647361;

__device__ __forceinline__ unsigned f2bf(float x){
  unsigned u = __float_as_uint(x);
  return (u + 0x7fffu + ((u >> 16) & 1u)) >> 16;   // RTNE
}

// ---------- prep: conv_qT (bid<1024) | conv_q (bid<1280) | lpos (else) ----------
__global__ __launch_bounds__(256) void prep_k(const float* __restrict__ q, const float* __restrict__ kk,
                                              const float* __restrict__ queue,
                                              unsigned short* __restrict__ qbf,
                                              unsigned short* __restrict__ qTbf,
                                              float* __restrict__ out, float* __restrict__ lposw){
  __shared__ float tile[128][65];
  const int bid = blockIdx.x, t = threadIdx.x;
  if (bid < 1024){                                  // queue [128][65536] -> qTbf [65536][128] bf16
    const int j0 = bid*64;
    #pragma unroll
    for (int it=0; it<8; ++it){                     // float4 reads: 128 rows x 16 f4
      int idx = it*256 + t;
      int d = idx >> 4, jj = (idx & 15)*4;
      float4 v = *(const float4*)(queue + (size_t)d*65536 + j0 + jj);
      tile[d][jj] = v.x; tile[d][jj+1] = v.y; tile[d][jj+2] = v.z; tile[d][jj+3] = v.w;
    }
    __syncthreads();
    #pragma unroll
    for (int it=0; it<8; ++it){                     // uint2 writes: 64 j x 32 d-quads
      int pidx = it*256 + t;
      int j = pidx >> 5, dq = (pidx & 31)*4;
      uint2 pk;
      pk.x = f2bf(tile[dq][j])   | (f2bf(tile[dq+1][j]) << 16);
      pk.y = f2bf(tile[dq+2][j]) | (f2bf(tile[dq+3][j]) << 16);
      *(uint2*)(qTbf + (size_t)(j0+j)*128 + dq) = pk;
    }
  } else if (bid < 1280){                           // q -> bf16
    int i = (bid-1024)*256 + t;
    const float4* q4 = (const float4*)q;
    float4 a = q4[2*i], b = q4[2*i+1];
    int4 st;
    st.x = (int)(f2bf(a.x) | (f2bf(a.y) << 16));
    st.y = (int)(f2bf(a.z) | (f2bf(a.w) << 16));
    st.z = (int)(f2bf(b.x) | (f2bf(b.y) << 16));
    st.w = (int)(f2bf(b.z) | (f2bf(b.w) << 16));
    ((int4*)qbf)[i] = st;
  } else {                                          // l_pos: 4 rows per block, 1 wave per row
    const int r = (bid-1280)*4 + (t>>6), l = t & 63;
    const float2* q2 = (const float2*)(q + (size_t)r*128);
    const float2* k2 = (const float2*)(kk + (size_t)r*128);
    float2 a = q2[l], b = k2[l];
    float s = a.x*b.x + a.y*b.y;
    #pragma unroll
    for (int o=1;o<64;o<<=1) s += __shfl_xor(s, o, 64);
    if (l == 0){
      float v = s * INV_TEMP;
      out[OUT_LOGITS + (size_t)r*65537] = v;
      lposw[r] = v;
    }
  }
}

// ---------- big GEMM: logits[:,1:] = (q @ queue)/TEMP, fused row sum-exp partials ----------
// R12: single-variable test vs R9 (gemm pinned ~340us across 3 read structures, amp
// 1.00x, FETCH varied 10x with no effect => limiter = store micro-pattern: every 64B
// segment at offset 4 mod 64 touches 2 lines). Fix = R5's rotation (aligned bulk
// segments: lanes lrow<rho shift +16 dwords and take vals[j+1]), which R5 tested only
// under the global-A churn confound. A+B LDS burst, one barrier, plain stores.
__global__ __launch_bounds__(512, 4) void gemm_k(const unsigned short* __restrict__ qbf,
                                                 const unsigned short* __restrict__ qTbf,
                                                 float* __restrict__ out,
                                                 float* __restrict__ partials){
  __shared__ unsigned char smem[65536];            // A 32KB | B 32KB, XOR-swizzled
  const int cbr = blockIdx.x;
  const int cb  = ((cbr & 7) << 6) | (cbr >> 3);   // XCD-chunked
  const int rb  = blockIdx.y;
  const int t   = threadIdx.x;
  const unsigned char* asrc = (const unsigned char*)qbf  + (size_t)rb*32768;
  const unsigned char* bsrc = (const unsigned char*)qTbf + (size_t)cb*32768;
  #pragma unroll
  for (int i=0;i<4;++i){
    int X = i*8192 + t*16;
    int row = X >> 8, off = X & 255;
    int sw = (row << 8) | (off ^ ((row & 7) << 4));
    *(bf16x8*)(smem + sw)         = *(const bf16x8*)(asrc + X);
    *(bf16x8*)(smem + 32768 + sw) = *(const bf16x8*)(bsrc + X);
  }
  __syncthreads();                                  // the only barrier
  const int l = t & 63, wid = t >> 6;               // 8 waves, wave owns 16 rows
  const int lrow = l & 15, lk = l >> 4;

  f32x4 acc[8];
  #pragma unroll
  for (int n=0;n<8;++n) acc[n] = (f32x4){0.f,0.f,0.f,0.f};
  #pragma unroll
  for (int kk2=0; kk2<4; ++kk2){
    const int koff = kk2*64 + lk*16;
    const int arow = wid*16 + lrow;
    bf16x8 af = *(const bf16x8*)(smem + ((arow << 8) | (koff ^ ((arow & 7) << 4))));
    bf16x8 bfr[8];
    #pragma unroll
    for (int n=0;n<8;++n){
      int col = n*16 + lrow;
      bfr[n] = *(const bf16x8*)(smem + 32768 + ((col << 8) | (koff ^ ((col & 7) << 4))));
    }
    #pragma unroll
    for (int n=0;n<8;++n)
      acc[n] = __builtin_amdgcn_mfma_f32_16x16x32_bf16(af, bfr[n], acc[n], 0, 0, 0);
  }
  // epilogue — no barriers; ALIGNED bulk stores via rotation (R5 scheme, de-confounded)
  #pragma unroll
  for (int r=0;r<4;++r){
    const size_t R = (size_t)rb*128 + wid*16 + lk*4 + r;         // global row
    const size_t rowstart = OUT_LOGITS + R*65537 + 1 + (size_t)cb*128;
    const int rho = (16 - ((int)(rowstart & 15))) & 15;          // rowstart+rho ≡ 0 mod 16
    const bool lofl = (lrow < rho);
    float vals[8]; float s = 0.f;
    #pragma unroll
    for (int n=0;n<8;++n){
      float v = acc[n][r] * INV_TEMP;
      vals[n] = v;
      s += __expf(v - M_REF);
    }
    float* base = out + rowstart + (lofl ? lrow + 16 : lrow);
    #pragma unroll
    for (int j=0;j<7;++j) base[j*16] = lofl ? vals[j+1] : vals[j];  // aligned 64B segments
    if (lofl) out[rowstart + lrow] = vals[0];                    // ragged head (rho dwords)
    else      out[rowstart + 112 + lrow] = vals[7];              // ragged tail (16-rho)
    #pragma unroll
    for (int o=1;o<16;o<<=1) s += __shfl_xor(s, o, 64);          // 16-lane row sum
    if (lrow == 0) partials[(size_t)cb*4096 + R] = s;
  }
}

// ---------- post: protos EMA (bid<100) | k6 (bid<4196) | rowsum (else) ----------
__global__ __launch_bounds__(128) void post_k(const float* __restrict__ q, const float* __restrict__ outp_in,
                                              const float* __restrict__ protos, const float* __restrict__ labels,
                                              const int* __restrict__ targets,
                                              const float* __restrict__ partials, const float* __restrict__ lposw,
                                              float* __restrict__ out, float* __restrict__ lcw,
                                              float* __restrict__ lpw, float* __restrict__ instw){
  __shared__ int   tg[4096];
  __shared__ int   mlist[4096];
  __shared__ int   cnt[128];
  __shared__ float red[128];
  __shared__ float qs[128];
  __shared__ float w2[2];
  const int bid = blockIdx.x, t = threadIdx.x;
  if (bid < 100){                                   // per-class prototype EMA via stable match list
    const int c = bid;
    for (int i=t;i<4096;i+=128) tg[i] = targets[i];
    __syncthreads();
    int myc = 0;
    #pragma unroll 4
    for (int i=0;i<32;++i) if (tg[t*32+i] == c) myc++;
    cnt[t] = myc; __syncthreads();
    // inclusive scan over 128 threads
    for (int s=1; s<128; s<<=1){
      int v = (t >= s) ? cnt[t-s] : 0;
      __syncthreads();
      cnt[t] += v;
      __syncthreads();
    }
    const int base = cnt[t] - myc;
    const int total = cnt[127];
    int k2 = base;
    for (int i=0;i<32;++i){
      int n = t*32 + i;
      if (tg[n] == c) mlist[k2++] = n;              // stable order: n ascending
    }
    __syncthreads();
    float val = protos[(size_t)c*128 + t];
    if (c != 0){
      for (int i=0;i<total;++i){
        int n = mlist[i];
        val = val*0.999f + 0.001f*q[(size_t)n*128 + t];
      }
    }
    red[t] = val*val; __syncthreads();
    #pragma unroll
    for (int s=64;s>0;s>>=1){ if (t < s) red[t] += red[t+s]; __syncthreads(); }
    float nrm = fmaxf(sqrtf(red[0]), 1e-12f);
    out[OUT_NPROTO + (size_t)c*128 + t] = val / nrm;
  } else if (bid < 4196){                           // logits_proto + both soft-CE rows + pred
    const int r = bid - 100;
    const int lane = t & 63, wid = t >> 6;
    qs[t] = q[(size_t)r*128 + t];
    __syncthreads();
    const bool act = t < 100;
    auto wmax = [&](float v)->float{
      #pragma unroll
      for (int o=1;o<64;o<<=1) v = fmaxf(v, __shfl_xor(v, o, 64));
      if (lane == 0) w2[wid] = v;
      __syncthreads();
      float rr = fmaxf(w2[0], w2[1]);
      __syncthreads();
      return rr;
    };
    auto wsum = [&](float v)->float{
      #pragma unroll
      for (int o=1;o<64;o<<=1) v += __shfl_xor(v, o, 64);
      if (lane == 0) w2[wid] = v;
      __syncthreads();
      float rr = w2[0] + w2[1];
      __syncthreads();
      return rr;
    };
    float p = 0.f;
    if (act){
      const float4* pr = (const float4*)(protos + (size_t)t*128);
      const float4* qv = (const float4*)qs;
      float s = 0.f;
      #pragma unroll 8
      for (int i=0;i<32;++i){ float4 a=qv[i], b=pr[i]; s += a.x*b.x + a.y*b.y + a.z*b.z + a.w*b.w; }
      p = s * INV_TEMP;
      out[OUT_LPROTO + (size_t)r*100 + t] = p;
    }
    const float lab = act ? labels[(size_t)r*100 + t] : 0.f;
    const float o   = act ? outp_in[(size_t)r*100 + t] : 0.f;
    float mx  = wmax(act ? p : -3.0e38f);
    float se  = wsum(act ? __expf(p - mx) : 0.f);
    float lse = mx + logf(se);
    float lpv = wsum(act ? lab * (p - lse) : 0.f);
    float mo   = wmax(act ? o : -3.0e38f);
    float seo  = wsum(act ? __expf(o - mo) : 0.f);
    float lseo = mo + logf(seo);
    float lcv  = wsum(act ? lab * (o - lseo) : 0.f);
    if (act) out[OUT_PRED + (size_t)r*100 + t] = (t > 0 && o >= mo) ? 1.f : 0.f;
    if (t == 0){ lpw[r] = lpv; lcw[r] = lcv; }
  } else {                                          // rowsum: inst log-softmax term
    const int r = (bid - 4196)*128 + t;
    float s = 0.f;
    for (int cbq=0; cbq<512; ++cbq) s += partials[(size_t)cbq*4096 + r];
    s += __expf(lposw[r] - M_REF);
    instw[r] = lposw[r] - M_REF - logf(s);
  }
}

// ---------- final scalar loss ----------
__global__ __launch_bounds__(256) void loss_k(const float* __restrict__ lcw, const float* __restrict__ lpw,
                                              const float* __restrict__ instw, float* __restrict__ out){
  __shared__ float red[256];
  const int t = threadIdx.x;
  float s = 0.f;
  for (int r=t;r<4096;r+=256) s += lcw[r] + lpw[r] + instw[r];
  red[t] = s; __syncthreads();
  for (int k2=128;k2>0;k2>>=1){ if (t<k2) red[t] += red[t+k2]; __syncthreads(); }
  if (t==0) out[OUT_LOSS] = -red[0] * (1.0f/4096.0f);
}

// ---------- new_queue: kt splice (bid<64) | copy (else, float4) ----------
__global__ __launch_bounds__(256) void newq_k(const float* __restrict__ queue, const float* __restrict__ kk,
                                              const int* __restrict__ ptrp, float* __restrict__ out){
  __shared__ float tile[64][129];
  const int bid = blockIdx.x, t = threadIdx.x;
  const int ptr = *ptrp;
  if (bid < 64){                                    // k.T into columns [ptr, ptr+4096)
    const int jb = bid;
    for (int it=0; it<32; ++it){
      int idx = it*256 + t;
      int j = idx >> 7, d = idx & 127;
      tile[j][d] = kk[(size_t)(jb*64 + j)*128 + d];
    }
    __syncthreads();
    for (int it=0; it<32; ++it){
      int idx = it*256 + t;
      int d = idx >> 6, j = idx & 63;
      out[OUT_NEWQ + (size_t)d*65536 + (size_t)(ptr + jb*64 + j)] = tile[j][d];
    }
  } else {                                          // copy outside splice, float4
    size_t tid4 = (size_t)(bid-64)*256 + t;
    for (size_t i4=tid4; i4<(size_t)2097152; i4 += (size_t)4096*256){
      size_t i = i4*4;
      int c = (int)(i & 65535);
      int lo = c - ptr;                              // elems lo..lo+3 vs [0,4096)
      if (lo + 3 < 0 || lo >= 4096){
        *(float4*)(out + OUT_NEWQ + i) = *(const float4*)(queue + i);
      } else {
        #pragma unroll
        for (int e=0;e<4;++e){
          int x = lo + e;
          if (x < 0 || x >= 4096) out[OUT_NEWQ + i + e] = queue[i + e];
        }
      }
    }
  }
}

extern "C" void kernel_launch(void* const* d_in, const int* in_sizes, int n_in,
                              void* d_out, int out_size, void* d_ws, size_t ws_size,
                              hipStream_t stream){
  const float* q      = (const float*)d_in[0];
  const float* k      = (const float*)d_in[1];
  const float* outp   = (const float*)d_in[2];
  const float* queue  = (const float*)d_in[3];
  const float* protos = (const float*)d_in[4];
  const float* labels = (const float*)d_in[5];
  const int*   targets= (const int*)d_in[6];
  const int*   ptrp   = (const int*)d_in[7];
  float* out = (float*)d_out;

  // Scratch lives inside the new_queue OUTPUT region (32 MiB; we use ~25.1 MiB).
  // new_queue is written LAST, after every scratch consumer has finished.
  uintptr_t scr = (uintptr_t)(out + OUT_NEWQ);
  scr = (scr + 255) & ~(uintptr_t)255;
  unsigned short* qbf  = (unsigned short*)scr;                          // 1 MB
  unsigned short* qTbf = (unsigned short*)(scr + (1u<<20));             // 16 MB
  float* partials      = (float*)(scr + (1u<<20) + (16u<<20));          // 8 MB
  float* lposw         = (float*)(scr + 26214400u);                     // 16 KB
  float* lcw           = (float*)(scr + 26230784u);                     // 16 KB
  float* lpw           = (float*)(scr + 26247168u);                     // 16 KB
  float* instw         = (float*)(scr + 26263552u);                     // 16 KB

  prep_k <<<2304, 256, 0, stream>>>(q, k, queue, qbf, qTbf, out, lposw);
  gemm_k <<<dim3(512,32), 512, 0, stream>>>(qbf, qTbf, out, partials);
  post_k <<<4228, 128, 0, stream>>>(q, outp, protos, labels, targets, partials, lposw,
                                    out, lcw, lpw, instw);
  loss_k <<<1, 256, 0, stream>>>(lcw, lpw, instw, out);
  newq_k <<<4160, 256, 0, stream>>>(queue, k, ptrp, out);

  (void)in_sizes; (void)n_in; (void)d_ws; (void)ws_size; (void)out_size;
}